// Round 1
// baseline (349.346 us; speedup 1.0000x reference)
//
#include <hip/hip_runtime.h>

// Guided filter, fully fused: one kernel, LDS tile with halo=2.
// Shapes: (8,16,512,512) fp32, KERNEL=3, EPS=0.01, count_include_pad=False.

constexpr int W  = 512;
constexpr int H  = 512;
constexpr int TW = 64;          // output tile width
constexpr int TH = 16;          // output tile height
constexpr int IW = TW + 4;      // 68: I/p halo tile width (halo 2 each side)
constexpr int IH = TH + 4;      // 20
constexpr int AW = TW + 2;      // 66: a/b tile width (halo 1 each side)
constexpr int AH = TH + 2;      // 18
constexpr float EPS = 0.01f;

__global__ __launch_bounds__(256) void guide_filter_kernel(
    const float* __restrict__ I, const float* __restrict__ P,
    float* __restrict__ O)
{
    __shared__ float sI[IH][IW];
    __shared__ float sP[IH][IW];
    __shared__ float sA[AH][AW];
    __shared__ float sB[AH][AW];

    const int tid = threadIdx.x;
    const int x0  = blockIdx.x * TW;
    const int y0  = blockIdx.y * TH;
    const size_t img_off = (size_t)blockIdx.z * (size_t)(W * H);
    const float* Ibase = I + img_off;
    const float* Pbase = P + img_off;
    float*       Obase = (float*)O + img_off;

    // ---- Stage 1: global -> LDS, zero-fill outside image (matches zero padding) ----
    for (int idx = tid; idx < IW * IH; idx += 256) {
        const int iy = idx / IW;
        const int ix = idx - iy * IW;
        const int gx = x0 - 2 + ix;
        const int gy = y0 - 2 + iy;
        float vi = 0.0f, vp = 0.0f;
        if (gx >= 0 && gx < W && gy >= 0 && gy < H) {
            const int g = gy * W + gx;
            vi = Ibase[g];
            vp = Pbase[g];
        }
        sI[iy][ix] = vi;
        sP[iy][ix] = vp;
    }
    __syncthreads();

    // ---- Stage 2: per-pixel a,b on the +1-halo region ----
    for (int idx = tid; idx < AW * AH; idx += 256) {
        const int ay  = idx / AW;
        const int ax  = idx - ay * AW;
        const int agx = x0 - 1 + ax;   // global coords of this a/b pixel
        const int agy = y0 - 1 + ay;
        float a = 0.0f, b = 0.0f;      // zero outside image: acts as the zero pad
        if (agx >= 0 && agx < W && agy >= 0 && agy < H) {
            float sIs = 0.f, sPs = 0.f, sII = 0.f, sIP = 0.f;
            #pragma unroll
            for (int dy = 0; dy < 3; ++dy) {
                #pragma unroll
                for (int dx = 0; dx < 3; ++dx) {
                    const float vi = sI[ay + dy][ax + dx];
                    const float vp = sP[ay + dy][ax + dx];
                    sIs += vi;
                    sPs += vp;
                    sII = fmaf(vi, vi, sII);
                    sIP = fmaf(vi, vp, sIP);
                }
            }
            // count_include_pad=False window counts
            const int cx = min(agx + 1, W - 1) - max(agx - 1, 0) + 1;
            const int cy = min(agy + 1, H - 1) - max(agy - 1, 0) + 1;
            const float inv = __builtin_amdgcn_rcpf((float)(cx * cy));
            const float mI  = sIs * inv;
            const float mP  = sPs * inv;
            const float varI = fmaf(-mI, mI, sII * inv);
            const float cov  = fmaf(-mI, mP, sIP * inv);
            a = cov * __builtin_amdgcn_rcpf(varI + EPS);
            b = fmaf(-a, mI, mP);
        }
        sA[ay][ax] = a;
        sB[ay][ax] = b;
    }
    __syncthreads();

    // ---- Stage 3: blur a,b; out = mean_a * I + mean_b ----
    for (int idx = tid; idx < TW * TH; idx += 256) {
        const int oy = idx >> 6;       // TW == 64
        const int ox = idx & 63;
        const int gx = x0 + ox;
        const int gy = y0 + oy;
        float sa = 0.f, sb = 0.f;
        #pragma unroll
        for (int dy = 0; dy < 3; ++dy) {
            #pragma unroll
            for (int dx = 0; dx < 3; ++dx) {
                sa += sA[oy + dy][ox + dx];
                sb += sB[oy + dy][ox + dx];
            }
        }
        const int cx = min(gx + 1, W - 1) - max(gx - 1, 0) + 1;
        const int cy = min(gy + 1, H - 1) - max(gy - 1, 0) + 1;
        const float inv = __builtin_amdgcn_rcpf((float)(cx * cy));
        const float ma = sa * inv;
        const float mb = sb * inv;
        Obase[gy * W + gx] = fmaf(ma, sI[oy + 2][ox + 2], mb);
    }
}

extern "C" void kernel_launch(void* const* d_in, const int* in_sizes, int n_in,
                              void* d_out, int out_size, void* d_ws, size_t ws_size,
                              hipStream_t stream) {
    const float* I = (const float*)d_in[0];   // input
    const float* P = (const float*)d_in[1];   // guide
    float*       O = (float*)d_out;
    const int images = in_sizes[0] / (W * H); // B*C = 128
    dim3 grid(W / TW, H / TH, images);
    guide_filter_kernel<<<grid, dim3(256), 0, stream>>>(I, P, O);
}

// Round 2
// 332.190 us; speedup vs baseline: 1.0516x; 1.0516x over previous
//
#include <hip/hip_runtime.h>

// Guided filter, fused single kernel. Round 2: LDS-traffic-optimized.
// - (I,P) interleaved as float2 in LDS; (a,b) interleaved as float2.
// - Stage 2: vertical strips of 6 a/b-rows per thread (8-row register window).
// - Stage 3: vertical strips of 4 output rows per thread.
// - Stage 1: float2 global loads + float4 LDS writes, conflict-free.
// Shapes: (8,16,512,512) fp32, KERNEL=3, EPS=0.01, count_include_pad=False.

constexpr int W  = 512;
constexpr int H  = 512;
constexpr int TW = 64;          // output tile width
constexpr int TH = 16;          // output tile height
constexpr int IW = TW + 4;      // 68 pair-columns (halo 2)
constexpr int IH = TH + 4;      // 20 rows
constexpr int AW = TW + 2;      // 66 (halo 1)
constexpr int AH = TH + 2;      // 18
constexpr float EPS = 0.01f;

__global__ __launch_bounds__(256) void guide_filter_kernel(
    const float* __restrict__ I, const float* __restrict__ P,
    float* __restrict__ O)
{
    __shared__ __align__(16) float2 sIP[IH][IW];   // (I, P) pairs
    __shared__ float2 sAB[AH][AW];                 // (a, b) pairs

    const int tid = threadIdx.x;
    const int x0  = blockIdx.x * TW;
    const int y0  = blockIdx.y * TH;
    const size_t img_off = (size_t)blockIdx.z * (size_t)(W * H);
    const float* Ibase = I + img_off;
    const float* Pbase = P + img_off;
    float*       Obase = (float*)O + img_off;

    // ---- Stage 1: global -> LDS. 34 float2-column tasks x 20 rows = 680. ----
    for (int t = tid; t < 34 * IH; t += 256) {
        const int row = t / 34;
        const int cp  = t - row * 34;          // float2 column-pair index
        const int gy  = y0 - 2 + row;
        const int gx  = x0 - 2 + 2 * cp;       // even -> 8B aligned
        float i0 = 0.f, i1 = 0.f, p0 = 0.f, p1 = 0.f;
        if (gy >= 0 && gy < H) {
            const int g = gy * W + gx;
            if (gx >= 0 && gx + 1 < W) {       // interior fast path
                const float2 vi = *(const float2*)(Ibase + g);
                const float2 vp = *(const float2*)(Pbase + g);
                i0 = vi.x; i1 = vi.y; p0 = vp.x; p1 = vp.y;
            } else {                            // x-edge blocks only
                if (gx >= 0 && gx < W)         { i0 = Ibase[g];     p0 = Pbase[g]; }
                if (gx + 1 >= 0 && gx + 1 < W) { i1 = Ibase[g + 1]; p1 = Pbase[g + 1]; }
            }
        }
        *(float4*)&sIP[row][2 * cp] = make_float4(i0, p0, i1, p1);
    }
    __syncthreads();

    // ---- Stage 2: a,b for the 66x18 halo region; 3 strips of 6 rows x 66 cols. ----
    if (tid < 3 * AW) {
        const int strip = tid / AW;            // 0..2
        const int ax    = tid - strip * AW;    // 0..65
        const int ay0   = strip * 6;

        float wI[6], wP[6], wII[6], wIP[6];
        #pragma unroll
        for (int j = 0; j < 6; ++j) { wI[j] = wP[j] = wII[j] = wIP[j] = 0.f; }

        #pragma unroll
        for (int c = 0; c < 3; ++c) {
            float2 v[8];
            #pragma unroll
            for (int j = 0; j < 8; ++j) v[j] = sIP[ay0 + j][ax + c];
            float ii[8], ip[8];
            #pragma unroll
            for (int j = 0; j < 8; ++j) {
                ii[j] = v[j].x * v[j].x;
                ip[j] = v[j].x * v[j].y;
            }
            #pragma unroll
            for (int j = 0; j < 6; ++j) {
                wI[j]  += v[j].x  + v[j + 1].x  + v[j + 2].x;
                wP[j]  += v[j].y  + v[j + 1].y  + v[j + 2].y;
                wII[j] += ii[j]   + ii[j + 1]   + ii[j + 2];
                wIP[j] += ip[j]   + ip[j + 1]   + ip[j + 2];
            }
        }

        const int gx = x0 - 1 + ax;
        const bool xok = (gx >= 0) & (gx < W);
        const float cx = 3.f - (float)(gx == 0) - (float)(gx == W - 1);
        #pragma unroll
        for (int j = 0; j < 6; ++j) {
            const int ay = ay0 + j;
            const int gy = y0 - 1 + ay;
            float a = 0.f, b = 0.f;            // zero outside image = zero pad
            if (xok & (gy >= 0) & (gy < H)) {
                const float cy  = 3.f - (float)(gy == 0) - (float)(gy == H - 1);
                const float inv = __builtin_amdgcn_rcpf(cx * cy);
                const float mI   = wI[j] * inv;
                const float mP   = wP[j] * inv;
                const float varI = fmaf(-mI, mI, wII[j] * inv);
                const float cov  = fmaf(-mI, mP, wIP[j] * inv);
                a = cov * __builtin_amdgcn_rcpf(varI + EPS);
                b = fmaf(-a, mI, mP);
            }
            sAB[ay][ax] = make_float2(a, b);
        }
    }
    __syncthreads();

    // ---- Stage 3: blur a,b; 4 strips of 4 output rows x 64 cols = 256 tasks. ----
    {
        const int x  = tid & 63;
        const int r0 = (tid >> 6) * 4;
        float2 ab[6][3];
        #pragma unroll
        for (int j = 0; j < 6; ++j)
            #pragma unroll
            for (int c = 0; c < 3; ++c)
                ab[j][c] = sAB[r0 + j][x + c];

        float hA[6], hB[6];
        #pragma unroll
        for (int j = 0; j < 6; ++j) {
            hA[j] = ab[j][0].x + ab[j][1].x + ab[j][2].x;
            hB[j] = ab[j][0].y + ab[j][1].y + ab[j][2].y;
        }

        const int gx = x0 + x;
        const float cx = 3.f - (float)(gx == 0) - (float)(gx == W - 1);
        #pragma unroll
        for (int j = 0; j < 4; ++j) {
            const int gy = y0 + r0 + j;
            const float cy  = 3.f - (float)(gy == 0) - (float)(gy == H - 1);
            const float inv = __builtin_amdgcn_rcpf(cx * cy);
            const float ma  = (hA[j] + hA[j + 1] + hA[j + 2]) * inv;
            const float mb  = (hB[j] + hB[j + 1] + hB[j + 2]) * inv;
            const float Ic  = sIP[r0 + j + 2][x + 2].x;
            Obase[gy * W + gx] = fmaf(ma, Ic, mb);
        }
    }
}

extern "C" void kernel_launch(void* const* d_in, const int* in_sizes, int n_in,
                              void* d_out, int out_size, void* d_ws, size_t ws_size,
                              hipStream_t stream) {
    const float* I = (const float*)d_in[0];   // input
    const float* P = (const float*)d_in[1];   // guide
    float*       O = (float*)d_out;
    const int images = in_sizes[0] / (W * H); // B*C = 128
    dim3 grid(W / TW, H / TH, images);
    guide_filter_kernel<<<grid, dim3(256), 0, stream>>>(I, P, O);
}

// Round 3
// 325.239 us; speedup vs baseline: 1.0741x; 1.0214x over previous
//
#include <hip/hip_runtime.h>

// Guided filter, fused single kernel. Round 3:
// - 64x32 tile, pair-column threads, all LDS access b128.
// - Register ring buffers for vertical 3-tap reuse in stages 2 & 3.
// - Interior-block specialization (no bounds code, counts == 9).
// - __launch_bounds__(256,4): 37.5KB LDS caps at 4 blocks/CU, so allow 128 VGPR.

constexpr int W  = 512;
constexpr int H  = 512;
constexpr int TW = 64;
constexpr int TH = 32;
constexpr int IPH = TH + 4;   // 36 rows of raw (I,P), halo 2
constexpr int IPW = TW + 4;   // 68 cols
constexpr int ABH = TH + 2;   // 34 rows of (a,b), halo 1
constexpr int ABW = TW + 2;   // 66 cols
constexpr float EPS  = 0.01f;
constexpr float INV9 = 1.0f / 9.0f;

template<bool INT>
__device__ __forceinline__ void run_tile(
    const float* __restrict__ Ibase, const float* __restrict__ Pbase,
    float* __restrict__ Obase, int x0, int y0, int tid,
    float2 (*sIP)[IPW], float2 (*sAB)[ABW])
{
    // ---- Stage 1: global -> LDS, (I,P) interleaved, b128 writes ----
    if (INT) {
        #pragma unroll 2
        for (int t = tid; t < 34 * IPH; t += 256) {
            const int row = t / 34;
            const int pc  = t - row * 34;
            const int g   = (y0 - 2 + row) * W + (x0 - 2 + 2 * pc);
            const float2 vi = *(const float2*)(Ibase + g);
            const float2 vp = *(const float2*)(Pbase + g);
            *(float4*)&sIP[row][2 * pc] = make_float4(vi.x, vp.x, vi.y, vp.y);
        }
    } else {
        for (int t = tid; t < 34 * IPH; t += 256) {
            const int row = t / 34;
            const int pc  = t - row * 34;
            const int gy  = y0 - 2 + row;
            const int gx  = x0 - 2 + 2 * pc;
            float i0 = 0.f, i1 = 0.f, q0 = 0.f, q1 = 0.f;
            if (gy >= 0 && gy < H) {
                const int g = gy * W + gx;
                if (gx >= 0 && gx + 1 < W) {
                    const float2 vi = *(const float2*)(Ibase + g);
                    const float2 vp = *(const float2*)(Pbase + g);
                    i0 = vi.x; i1 = vi.y; q0 = vp.x; q1 = vp.y;
                } else {
                    if ((unsigned)gx < (unsigned)W)       { i0 = Ibase[g];     q0 = Pbase[g]; }
                    if ((unsigned)(gx + 1) < (unsigned)W) { i1 = Ibase[g + 1]; q1 = Pbase[g + 1]; }
                }
            }
            *(float4*)&sIP[row][2 * pc] = make_float4(i0, q0, i1, q1);
        }
    }
    __syncthreads();

    // ---- Stage 2: a,b for 66x34 region. 33 pair-cols x 7 row-strips. ----
    if (tid < 231) {
        const int p    = tid % 33;        // ab cols 2p, 2p+1 -> needs sIP cols 2p..2p+3
        const int s    = tid / 33;        // ab rows 5s..min(5s+4,33)
        const int row0 = 5 * s;

        float hI[2][3], hP[2][3], hII[2][3], hIP[2][3];
        #pragma unroll
        for (int j = 0; j < 7; ++j) {
            int rr = row0 + j; rr = rr > IPH - 1 ? IPH - 1 : rr;
            const float4 c01 = *(const float4*)&sIP[rr][2 * p];
            const float4 c23 = *(const float4*)&sIP[rr][2 * p + 2];
            const float i0 = c01.x, q0 = c01.y, i1 = c01.z, q1 = c01.w;
            const float i2 = c23.x, q2 = c23.y, i3 = c23.z, q3 = c23.w;
            const int k = j % 3;
            const float tI  = i1 + i2, tP = q1 + q2;
            const float tII = fmaf(i1, i1, i2 * i2);
            const float tIP = fmaf(i1, q1, i2 * q2);
            hI[0][k]  = tI + i0;            hI[1][k]  = tI + i3;
            hP[0][k]  = tP + q0;            hP[1][k]  = tP + q3;
            hII[0][k] = fmaf(i0, i0, tII);  hII[1][k] = fmaf(i3, i3, tII);
            hIP[0][k] = fmaf(i0, q0, tIP);  hIP[1][k] = fmaf(i3, q3, tIP);
            if (j >= 2) {
                const int ay = row0 + j - 2;
                if (ay < ABH) {
                    float ab[4];
                    #pragma unroll
                    for (int c = 0; c < 2; ++c) {
                        const float wI  = hI[c][0]  + hI[c][1]  + hI[c][2];
                        const float wP  = hP[c][0]  + hP[c][1]  + hP[c][2];
                        const float wII = hII[c][0] + hII[c][1] + hII[c][2];
                        const float wIP = hIP[c][0] + hIP[c][1] + hIP[c][2];
                        float a = 0.f, b = 0.f;
                        if (INT) {
                            const float mI   = wI * INV9, mP = wP * INV9;
                            const float varI = fmaf(-mI, mI, wII * INV9);
                            const float cov  = fmaf(-mI, mP, wIP * INV9);
                            a = cov * __builtin_amdgcn_rcpf(varI + EPS);
                            b = fmaf(-a, mI, mP);
                        } else {
                            const int gx = x0 - 1 + 2 * p + c;
                            const int gy = y0 - 1 + ay;
                            if ((unsigned)gx < (unsigned)W && (unsigned)gy < (unsigned)H) {
                                const float cx = 3.f - (float)(gx == 0) - (float)(gx == W - 1);
                                const float cy = 3.f - (float)(gy == 0) - (float)(gy == H - 1);
                                const float inv  = __builtin_amdgcn_rcpf(cx * cy);
                                const float mI   = wI * inv, mP = wP * inv;
                                const float varI = fmaf(-mI, mI, wII * inv);
                                const float cov  = fmaf(-mI, mP, wIP * inv);
                                a = cov * __builtin_amdgcn_rcpf(varI + EPS);
                                b = fmaf(-a, mI, mP);
                            }
                        }
                        ab[2 * c] = a; ab[2 * c + 1] = b;
                    }
                    *(float4*)&sAB[ay][2 * p] = make_float4(ab[0], ab[1], ab[2], ab[3]);
                }
            }
        }
    }
    __syncthreads();

    // ---- Stage 3: blur a,b; 32 out col-pairs x 8 strips of 4 rows. ----
    {
        const int q   = tid & 31;
        const int r   = tid >> 5;
        const int ox0 = 2 * q;
        const int oy0 = 4 * r;
        float hA[2][3], hB[2][3];
        #pragma unroll
        for (int j = 0; j < 6; ++j) {
            const float4 c01 = *(const float4*)&sAB[oy0 + j][ox0];
            const float4 c23 = *(const float4*)&sAB[oy0 + j][ox0 + 2];
            const float a0 = c01.x, b0 = c01.y, a1 = c01.z, b1 = c01.w;
            const float a2 = c23.x, b2 = c23.y, a3 = c23.z, b3 = c23.w;
            const int k = j % 3;
            const float tA = a1 + a2, tB = b1 + b2;
            hA[0][k] = tA + a0; hA[1][k] = tA + a3;
            hB[0][k] = tB + b0; hB[1][k] = tB + b3;
            if (j >= 2) {
                const int oy = oy0 + j - 2;
                const float4 ic = *(const float4*)&sIP[oy + 2][ox0 + 2];
                float res[2];
                #pragma unroll
                for (int c = 0; c < 2; ++c) {
                    const float sa = hA[c][0] + hA[c][1] + hA[c][2];
                    const float sb = hB[c][0] + hB[c][1] + hB[c][2];
                    float inv;
                    if (INT) {
                        inv = INV9;
                    } else {
                        const int gx = x0 + ox0 + c, gy = y0 + oy;
                        const float cx = 3.f - (float)(gx == 0) - (float)(gx == W - 1);
                        const float cy = 3.f - (float)(gy == 0) - (float)(gy == H - 1);
                        inv = __builtin_amdgcn_rcpf(cx * cy);
                    }
                    const float Ic = (c == 0) ? ic.x : ic.z;
                    res[c] = fmaf(sa * inv, Ic, sb * inv);
                }
                *(float2*)(Obase + (y0 + oy) * W + x0 + ox0) = make_float2(res[0], res[1]);
            }
        }
    }
}

__global__ __launch_bounds__(256, 4) void guide_filter_kernel(
    const float* __restrict__ I, const float* __restrict__ P,
    float* __restrict__ O)
{
    __shared__ __align__(16) float2 sIP[IPH][IPW];
    __shared__ __align__(16) float2 sAB[ABH][ABW];

    const int tid = threadIdx.x;
    const int x0  = blockIdx.x * TW;
    const int y0  = blockIdx.y * TH;
    const size_t img_off = (size_t)blockIdx.z * (size_t)(W * H);
    const bool interior = (blockIdx.x > 0) & (blockIdx.x < gridDim.x - 1) &
                          (blockIdx.y > 0) & (blockIdx.y < gridDim.y - 1);
    if (interior) {
        run_tile<true >(I + img_off, P + img_off, (float*)O + img_off, x0, y0, tid, sIP, sAB);
    } else {
        run_tile<false>(I + img_off, P + img_off, (float*)O + img_off, x0, y0, tid, sIP, sAB);
    }
}

extern "C" void kernel_launch(void* const* d_in, const int* in_sizes, int n_in,
                              void* d_out, int out_size, void* d_ws, size_t ws_size,
                              hipStream_t stream) {
    const float* I = (const float*)d_in[0];   // input
    const float* P = (const float*)d_in[1];   // guide
    float*       O = (float*)d_out;
    const int images = in_sizes[0] / (W * H); // B*C = 128
    dim3 grid(W / TW, H / TH, images);
    guide_filter_kernel<<<grid, dim3(256), 0, stream>>>(I, P, O);
}

// Round 4
// 317.979 us; speedup vs baseline: 1.0986x; 1.0228x over previous
//
#include <hip/hip_runtime.h>

// Guided filter, fused single kernel. Round 4:
// - 64x16 tile: LDS 20.4KB -> 7 blocks/CU (28 waves) for cross-block overlap.
// - All LDS access b128; register ring buffers for vertical 3-taps.
// - Stage-3 center I comes from GLOBAL (L1/L2 hit) not LDS: offloads LDS pipe.
// - Interior-block specialization (counts == 9, no bounds code).

constexpr int W  = 512;
constexpr int H  = 512;
constexpr int TW = 64;
constexpr int TH = 16;
constexpr int IPH = TH + 4;   // 20 rows of raw (I,P), halo 2
constexpr int IPW = TW + 4;   // 68 cols
constexpr int ABH = TH + 2;   // 18 rows of (a,b), halo 1
constexpr int ABW = TW + 2;   // 66 cols
constexpr float EPS  = 0.01f;
constexpr float INV9 = 1.0f / 9.0f;

template<bool INT>
__device__ __forceinline__ void run_tile(
    const float* __restrict__ Ibase, const float* __restrict__ Pbase,
    float* __restrict__ Obase, int x0, int y0, int tid,
    float2 (*sIP)[IPW], float2 (*sAB)[ABW])
{
    // ---- Stage 1: global -> LDS, (I,P) interleaved, b128 writes. 34x20 tasks ----
    if (INT) {
        for (int t = tid; t < 34 * IPH; t += 256) {
            const int row = t / 34;
            const int pc  = t - row * 34;
            const int g   = (y0 - 2 + row) * W + (x0 - 2 + 2 * pc);
            const float2 vi = *(const float2*)(Ibase + g);
            const float2 vp = *(const float2*)(Pbase + g);
            *(float4*)&sIP[row][2 * pc] = make_float4(vi.x, vp.x, vi.y, vp.y);
        }
    } else {
        for (int t = tid; t < 34 * IPH; t += 256) {
            const int row = t / 34;
            const int pc  = t - row * 34;
            const int gy  = y0 - 2 + row;
            const int gx  = x0 - 2 + 2 * pc;
            float i0 = 0.f, i1 = 0.f, q0 = 0.f, q1 = 0.f;
            if (gy >= 0 && gy < H) {
                const int g = gy * W + gx;
                if (gx >= 0 && gx + 1 < W) {
                    const float2 vi = *(const float2*)(Ibase + g);
                    const float2 vp = *(const float2*)(Pbase + g);
                    i0 = vi.x; i1 = vi.y; q0 = vp.x; q1 = vp.y;
                } else {
                    if ((unsigned)gx < (unsigned)W)       { i0 = Ibase[g];     q0 = Pbase[g]; }
                    if ((unsigned)(gx + 1) < (unsigned)W) { i1 = Ibase[g + 1]; q1 = Pbase[g + 1]; }
                }
            }
            *(float4*)&sIP[row][2 * pc] = make_float4(i0, q0, i1, q1);
        }
    }
    __syncthreads();

    // ---- Stage 2: a,b for 66x18 region. 33 pair-cols x 3 strips of 6 rows. ----
    if (tid < 99) {
        const int p    = tid % 33;        // ab cols 2p, 2p+1 -> needs sIP cols 2p..2p+3
        const int s    = tid / 33;        // 0..2
        const int row0 = 6 * s;           // raw rows row0..row0+7 (<= 19)

        float hI[2][3], hP[2][3], hII[2][3], hIP[2][3];
        #pragma unroll
        for (int j = 0; j < 8; ++j) {
            const int rr = row0 + j;
            const float4 c01 = *(const float4*)&sIP[rr][2 * p];
            const float4 c23 = *(const float4*)&sIP[rr][2 * p + 2];
            const float i0 = c01.x, q0 = c01.y, i1 = c01.z, q1 = c01.w;
            const float i2 = c23.x, q2 = c23.y, i3 = c23.z, q3 = c23.w;
            const int k = j % 3;
            const float tI  = i1 + i2, tP = q1 + q2;
            const float tII = fmaf(i1, i1, i2 * i2);
            const float tIP = fmaf(i1, q1, i2 * q2);
            hI[0][k]  = tI + i0;            hI[1][k]  = tI + i3;
            hP[0][k]  = tP + q0;            hP[1][k]  = tP + q3;
            hII[0][k] = fmaf(i0, i0, tII);  hII[1][k] = fmaf(i3, i3, tII);
            hIP[0][k] = fmaf(i0, q0, tIP);  hIP[1][k] = fmaf(i3, q3, tIP);
            if (j >= 2) {
                const int ay = row0 + j - 2;        // 6 ab rows per strip
                float ab[4];
                #pragma unroll
                for (int c = 0; c < 2; ++c) {
                    const float wI  = hI[c][0]  + hI[c][1]  + hI[c][2];
                    const float wP  = hP[c][0]  + hP[c][1]  + hP[c][2];
                    const float wII = hII[c][0] + hII[c][1] + hII[c][2];
                    const float wIP = hIP[c][0] + hIP[c][1] + hIP[c][2];
                    float a = 0.f, b = 0.f;
                    if (INT) {
                        const float mI   = wI * INV9, mP = wP * INV9;
                        const float varI = fmaf(-mI, mI, wII * INV9);
                        const float cov  = fmaf(-mI, mP, wIP * INV9);
                        a = cov * __builtin_amdgcn_rcpf(varI + EPS);
                        b = fmaf(-a, mI, mP);
                    } else {
                        const int gx = x0 - 1 + 2 * p + c;
                        const int gy = y0 - 1 + ay;
                        if ((unsigned)gx < (unsigned)W && (unsigned)gy < (unsigned)H) {
                            const float cx = 3.f - (float)(gx == 0) - (float)(gx == W - 1);
                            const float cy = 3.f - (float)(gy == 0) - (float)(gy == H - 1);
                            const float inv  = __builtin_amdgcn_rcpf(cx * cy);
                            const float mI   = wI * inv, mP = wP * inv;
                            const float varI = fmaf(-mI, mI, wII * inv);
                            const float cov  = fmaf(-mI, mP, wIP * inv);
                            a = cov * __builtin_amdgcn_rcpf(varI + EPS);
                            b = fmaf(-a, mI, mP);
                        }
                    }
                    ab[2 * c] = a; ab[2 * c + 1] = b;
                }
                *(float4*)&sAB[ay][2 * p] = make_float4(ab[0], ab[1], ab[2], ab[3]);
            }
        }
    }
    __syncthreads();

    // ---- Stage 3: blur a,b; 32 out col-pairs x 4 strips of 4 rows = 128 threads. ----
    if (tid < 128) {
        const int q   = tid & 31;
        const int r   = tid >> 5;         // 0..3
        const int ox0 = 2 * q;
        const int oy0 = 4 * r;            // ab rows oy0..oy0+5 (<=17)
        float hA[2][3], hB[2][3];
        #pragma unroll
        for (int j = 0; j < 6; ++j) {
            const float4 c01 = *(const float4*)&sAB[oy0 + j][ox0];
            const float4 c23 = *(const float4*)&sAB[oy0 + j][ox0 + 2];
            const float a0 = c01.x, b0 = c01.y, a1 = c01.z, b1 = c01.w;
            const float a2 = c23.x, b2 = c23.y, a3 = c23.z, b3 = c23.w;
            const int k = j % 3;
            const float tA = a1 + a2, tB = b1 + b2;
            hA[0][k] = tA + a0; hA[1][k] = tA + a3;
            hB[0][k] = tB + b0; hB[1][k] = tB + b3;
            if (j >= 2) {
                const int oy = oy0 + j - 2;
                const int gy = y0 + oy;
                const int go = gy * W + x0 + ox0;
                const float2 iv = *(const float2*)(Ibase + go);   // L1/L2 hit
                float res[2];
                #pragma unroll
                for (int c = 0; c < 2; ++c) {
                    const float sa = hA[c][0] + hA[c][1] + hA[c][2];
                    const float sb = hB[c][0] + hB[c][1] + hB[c][2];
                    float inv;
                    if (INT) {
                        inv = INV9;
                    } else {
                        const int gx = x0 + ox0 + c;
                        const float cx = 3.f - (float)(gx == 0) - (float)(gx == W - 1);
                        const float cy = 3.f - (float)(gy == 0) - (float)(gy == H - 1);
                        inv = __builtin_amdgcn_rcpf(cx * cy);
                    }
                    const float Ic = (c == 0) ? iv.x : iv.y;
                    res[c] = fmaf(sa * inv, Ic, sb * inv);
                }
                *(float2*)(Obase + go) = make_float2(res[0], res[1]);
            }
        }
    }
}

__global__ __launch_bounds__(256, 7) void guide_filter_kernel(
    const float* __restrict__ I, const float* __restrict__ P,
    float* __restrict__ O)
{
    __shared__ __align__(16) float2 sIP[IPH][IPW];
    __shared__ __align__(16) float2 sAB[ABH][ABW];

    const int tid = threadIdx.x;
    const int x0  = blockIdx.x * TW;
    const int y0  = blockIdx.y * TH;
    const size_t img_off = (size_t)blockIdx.z * (size_t)(W * H);
    const bool interior = (blockIdx.x > 0) & (blockIdx.x < gridDim.x - 1) &
                          (blockIdx.y > 0) & (blockIdx.y < gridDim.y - 1);
    if (interior) {
        run_tile<true >(I + img_off, P + img_off, (float*)O + img_off, x0, y0, tid, sIP, sAB);
    } else {
        run_tile<false>(I + img_off, P + img_off, (float*)O + img_off, x0, y0, tid, sIP, sAB);
    }
}

extern "C" void kernel_launch(void* const* d_in, const int* in_sizes, int n_in,
                              void* d_out, int out_size, void* d_ws, size_t ws_size,
                              hipStream_t stream) {
    const float* I = (const float*)d_in[0];   // input
    const float* P = (const float*)d_in[1];   // guide
    float*       O = (float*)d_out;
    const int images = in_sizes[0] / (W * H); // B*C = 128
    dim3 grid(W / TW, H / TH, images);
    guide_filter_kernel<<<grid, dim3(256), 0, stream>>>(I, P, O);
}